// Round 4
// baseline (333.433 us; speedup 1.0000x reference)
//
#include <hip/hip_runtime.h>
#include <hip/hip_cooperative_groups.h>

namespace cg = cooperative_groups;

#define DD 128
#define FF 512
#define BAGS 5000
#define RPG 16   // consecutive rows per 32-lane group
#define GRID 1954
#define BLK 256

// Monotonic uint key for f32: preserves float ordering under unsigned compare.
__device__ __forceinline__ unsigned fkey(float f) {
    unsigned u = __float_as_uint(f);
    return (u & 0x80000000u) ? ~u : (u | 0x80000000u);
}
// Inverse of fkey (bijective).
__device__ __forceinline__ float fkey_inv(unsigned k) {
    unsigned u = (k & 0x80000000u) ? (k & 0x7FFFFFFFu) : ~k;
    return __uint_as_float(u);
}

__global__ __launch_bounds__(BLK, 8) void fused_kernel(
    const float* __restrict__ z, const float* __restrict__ W, const float* __restrict__ b,
    const int* __restrict__ bag, const float* __restrict__ inst,
    const float* __restrict__ mu, const float* __restrict__ stdv,
    float* __restrict__ loc, unsigned long long* __restrict__ packed,
    float* __restrict__ oM, float* __restrict__ oInst, float* __restrict__ oZ,
    float* __restrict__ oMu, float* __restrict__ oStd, int N)
{
    cg::grid_group grid = cg::this_grid();

    // ---- Phase 1: zero the per-bag packed (key,idx) array ----
    for (int j = blockIdx.x * blockDim.x + threadIdx.x; j < BAGS;
         j += gridDim.x * blockDim.x)
        packed[j] = 0ull;
    grid.sync();

    // ---- Phase 2: loc = z@W + b, fused per-bag packed max (sorted bags) ----
    {
        int lane = threadIdx.x & 31;
        long long gidx = (long long)blockIdx.x * (blockDim.x >> 5) + (threadIdx.x >> 5);
        long long row0 = gidx * RPG;
        if (row0 < N) {
            float4 wv = ((const float4*)W)[lane];
            float bb = b[0];
            int rcnt = (int)((N - row0 < RPG) ? (N - row0) : RPG);
            unsigned long long best = 0ull;
            int curbag = -1;
            for (int j = 0; j < rcnt; ++j) {
                long long row = row0 + j;
                float4 zv = ((const float4*)(z + row * DD))[lane];
                float s = zv.x * wv.x + zv.y * wv.y + zv.z * wv.z + zv.w * wv.w;
                #pragma unroll
                for (int off = 16; off >= 1; off >>= 1) s += __shfl_xor(s, off, 32);
                if (lane == 0) {
                    s += bb;
                    loc[row] = s;
                    unsigned long long key =
                        ((unsigned long long)fkey(s) << 32) | (unsigned)(N - 1 - (int)row);
                    int bg = bag[row];
                    if (bg != curbag) {
                        if (curbag >= 0) atomicMax(&packed[curbag], best);
                        curbag = bg;
                        best = key;
                    } else if (key > best) {
                        best = key;
                    }
                }
            }
            if (lane == 0 && curbag >= 0) atomicMax(&packed[curbag], best);
        }
    }
    grid.sync();

    // ---- Phase 3: gather argmax rows (zeros for empty bags) ----
    for (int bagi = blockIdx.x; bagi < BAGS; bagi += gridDim.x) {
        unsigned long long p = packed[bagi];
        bool empty = (p == 0ull);
        long long ac = empty ? 0 : (long long)(N - 1 - (int)(unsigned)(p & 0xFFFFFFFFull));
        const float4 zero4 = make_float4(0.f, 0.f, 0.f, 0.f);
        int t = threadIdx.x;
        if (t < 128) {
            float4 v = empty ? zero4 : ((const float4*)(inst + ac * FF))[t];
            ((float4*)(oInst + (long long)bagi * FF))[t] = v;
        } else if (t < 160) {
            int k = t - 128;
            float4 v = empty ? zero4 : ((const float4*)(z + ac * DD))[k];
            ((float4*)(oZ + (long long)bagi * DD))[k] = v;
        } else if (t < 192) {
            int k = t - 160;
            float4 v = empty ? zero4 : ((const float4*)(mu + ac * DD))[k];
            ((float4*)(oMu + (long long)bagi * DD))[k] = v;
        } else if (t < 224) {
            int k = t - 192;
            float4 v = empty ? zero4 : ((const float4*)(stdv + ac * DD))[k];
            ((float4*)(oStd + (long long)bagi * DD))[k] = v;
        } else if (t == 224) {
            oM[bagi] = empty ? 0.f : fkey_inv((unsigned)(p >> 32));
        }
    }
}

extern "C" void kernel_launch(void* const* d_in, const int* in_sizes, int n_in,
                              void* d_out, int out_size, void* d_ws, size_t ws_size,
                              hipStream_t stream) {
    const float* z    = (const float*)d_in[0];
    const int*   bag  = (const int*)d_in[1];
    const float* inst = (const float*)d_in[2];
    const float* mu   = (const float*)d_in[3];
    const float* stdv = (const float*)d_in[4];
    const float* W    = (const float*)d_in[5];
    const float* b    = (const float*)d_in[6];
    int N = in_sizes[1];

    float* out = (float*)d_out;
    // Output layout (flat, return order): M | max_instances | max_z_ins | loc_ins | mu | std
    long long off_inst = BAGS;
    long long off_z    = off_inst + (long long)BAGS * FF;
    long long off_loc  = off_z    + (long long)BAGS * DD;
    long long off_mu   = off_loc  + N;
    long long off_std  = off_mu   + (long long)BAGS * DD;

    unsigned long long* packed = (unsigned long long*)d_ws;
    float* loc  = out + off_loc;
    float* oM   = out;
    float* oInst= out + off_inst;
    float* oZ   = out + off_z;
    float* oMu  = out + off_mu;
    float* oStd = out + off_std;

    void* args[] = { (void*)&z, (void*)&W, (void*)&b, (void*)&bag, (void*)&inst,
                     (void*)&mu, (void*)&stdv, (void*)&loc, (void*)&packed,
                     (void*)&oM, (void*)&oInst, (void*)&oZ, (void*)&oMu,
                     (void*)&oStd, (void*)&N };
    hipLaunchCooperativeKernel((const void*)fused_kernel, dim3(GRID), dim3(BLK),
                               args, 0, stream);
}

// Round 5
// 44.040 us; speedup vs baseline: 7.5712x; 7.5712x over previous
//
#include <hip/hip_runtime.h>

#define DD 128
#define FF 512
#define BAGS 5000

// Monotonic uint key for f32: preserves float ordering under unsigned compare.
__device__ __forceinline__ unsigned fkey(float f) {
    unsigned u = __float_as_uint(f);
    return (u & 0x80000000u) ? ~u : (u | 0x80000000u);
}
// Inverse of fkey (bijective).
__device__ __forceinline__ float fkey_inv(unsigned k) {
    unsigned u = (k & 0x80000000u) ? (k & 0x7FFFFFFFu) : ~k;
    return __uint_as_float(u);
}

// One block per bag (bags are contiguous in sorted bag_idx):
//   1) binary-search the bag's row range [s,e)
//   2) compute loc for those rows (write loc_ins), tracking packed max in regs
//   3) LDS-reduce the 8 group partials
//   4) gather the argmax row of all arrays (zeros if empty)
__global__ __launch_bounds__(256) void fused_bag_kernel(
    const float* __restrict__ z, const int* __restrict__ bag,
    const float* __restrict__ inst, const float* __restrict__ mu,
    const float* __restrict__ stdv, const float* __restrict__ W,
    const float* __restrict__ b,
    float* __restrict__ oM, float* __restrict__ oInst, float* __restrict__ oZ,
    float* __restrict__ oMu, float* __restrict__ oStd, float* __restrict__ loc,
    int N)
{
    __shared__ int s_se[2];
    __shared__ unsigned long long s_best[8];

    int bagi = blockIdx.x;
    if (threadIdx.x < 2) {
        int target = bagi + (int)threadIdx.x;   // lower_bound(bag_idx, target)
        int lo = 0, hi = N;
        while (lo < hi) {
            int mid = (lo + hi) >> 1;
            if (bag[mid] < target) lo = mid + 1; else hi = mid;
        }
        s_se[threadIdx.x] = lo;
    }
    __syncthreads();
    int s = s_se[0], e = s_se[1];

    int lane = threadIdx.x & 31;
    int grp  = threadIdx.x >> 5;            // 8 groups of 32 lanes
    float4 wv = ((const float4*)W)[lane];
    float bb = b[0];

    unsigned long long best = 0ull;
    for (int r = s + grp; r < e; r += 8) {
        float4 zv = ((const float4*)(z + (long long)r * DD))[lane];
        float sd = fmaf(zv.x, wv.x, fmaf(zv.y, wv.y, fmaf(zv.z, wv.z, zv.w * wv.w)));
        #pragma unroll
        for (int off = 16; off >= 1; off >>= 1) sd += __shfl_xor(sd, off, 32);
        if (lane == 0) {
            sd += bb;
            loc[r] = sd;
            unsigned long long key =
                ((unsigned long long)fkey(sd) << 32) | (unsigned)(N - 1 - r);
            if (key > best) best = key;
        }
    }
    if (lane == 0) s_best[grp] = best;
    __syncthreads();
    if (threadIdx.x == 0) {
        unsigned long long m = s_best[0];
        #pragma unroll
        for (int g = 1; g < 8; ++g) if (s_best[g] > m) m = s_best[g];
        s_best[0] = m;
    }
    __syncthreads();

    unsigned long long p = s_best[0];
    bool empty = (e <= s);
    long long ac = empty ? 0 : (long long)(N - 1 - (int)(unsigned)(p & 0xFFFFFFFFull));
    const float4 zero4 = make_float4(0.f, 0.f, 0.f, 0.f);
    int t = threadIdx.x;
    if (t < 128) {
        float4 v = empty ? zero4 : ((const float4*)(inst + ac * FF))[t];
        ((float4*)(oInst + (long long)bagi * FF))[t] = v;
    } else if (t < 160) {
        int k = t - 128;
        float4 v = empty ? zero4 : ((const float4*)(z + ac * DD))[k];
        ((float4*)(oZ + (long long)bagi * DD))[k] = v;
    } else if (t < 192) {
        int k = t - 160;
        float4 v = empty ? zero4 : ((const float4*)(mu + ac * DD))[k];
        ((float4*)(oMu + (long long)bagi * DD))[k] = v;
    } else if (t < 224) {
        int k = t - 192;
        float4 v = empty ? zero4 : ((const float4*)(stdv + ac * DD))[k];
        ((float4*)(oStd + (long long)bagi * DD))[k] = v;
    } else if (t == 224) {
        oM[bagi] = empty ? 0.f : fkey_inv((unsigned)(p >> 32));
    }
}

extern "C" void kernel_launch(void* const* d_in, const int* in_sizes, int n_in,
                              void* d_out, int out_size, void* d_ws, size_t ws_size,
                              hipStream_t stream) {
    const float* z    = (const float*)d_in[0];
    const int*   bag  = (const int*)d_in[1];
    const float* inst = (const float*)d_in[2];
    const float* mu   = (const float*)d_in[3];
    const float* stdv = (const float*)d_in[4];
    const float* W    = (const float*)d_in[5];
    const float* b    = (const float*)d_in[6];
    int N = in_sizes[1];

    float* out = (float*)d_out;
    // Output layout (flat, return order): M | max_instances | max_z_ins | loc_ins | mu | std
    long long off_inst = BAGS;
    long long off_z    = off_inst + (long long)BAGS * FF;
    long long off_loc  = off_z    + (long long)BAGS * DD;
    long long off_mu   = off_loc  + N;
    long long off_std  = off_mu   + (long long)BAGS * DD;

    fused_bag_kernel<<<BAGS, 256, 0, stream>>>(
        z, bag, inst, mu, stdv, W, b,
        out, out + off_inst, out + off_z, out + off_mu, out + off_std,
        out + off_loc, N);
}

// Round 6
// 40.033 us; speedup vs baseline: 8.3290x; 1.1001x over previous
//
#include <hip/hip_runtime.h>

#define DD 128
#define FF 512
#define BAGS 5000

// Monotonic uint key for f32: preserves float ordering under unsigned compare.
__device__ __forceinline__ unsigned fkey(float f) {
    unsigned u = __float_as_uint(f);
    return (u & 0x80000000u) ? ~u : (u | 0x80000000u);
}
// Inverse of fkey (bijective).
__device__ __forceinline__ float fkey_inv(unsigned k) {
    unsigned u = (k & 0x80000000u) ? (k & 0x7FFFFFFFu) : ~k;
    return __uint_as_float(u);
}

// loc = z@W + b with 4 lanes per row (quad). Each wave64 covers 16 rows/tile,
// 4 tiles => 256 rows per block of 256 threads. Per-bag packed (fkey,idx) max
// via wave-segmented suffix-max over row slots (bag_idx sorted), ~1.3 atomics
// per 16 rows.
__global__ __launch_bounds__(256) void loc_seg_kernel(
    const float* __restrict__ z, const int* __restrict__ bag,
    const float* __restrict__ W, const float* __restrict__ b,
    float* __restrict__ loc, unsigned long long* __restrict__ packed, int N)
{
    int tid  = threadIdx.x;
    int lane = tid & 63;
    int wave = tid >> 6;              // 0..3
    int ll   = lane & 3;              // chunk-quad position within row
    int rowslot = lane >> 2;          // 0..15

    long long wavebase = (long long)blockIdx.x * 256 + wave * 64;

    float4 wk[8];                     // this lane's 8 W chunks (k = ll + 4j)
    #pragma unroll
    for (int j = 0; j < 8; ++j) wk[j] = ((const float4*)W)[ll + 4 * j];
    float bb = b[0];

    #pragma unroll
    for (int t = 0; t < 4; ++t) {
        long long row = wavebase + t * 16 + rowslot;
        bool valid = row < N;
        float4 acc = make_float4(0.f, 0.f, 0.f, 0.f);
        if (valid) {
            const float4* zr = (const float4*)(z + row * DD);
            #pragma unroll
            for (int j = 0; j < 8; ++j) {
                float4 zv = zr[ll + 4 * j];
                acc.x = fmaf(zv.x, wk[j].x, acc.x);
                acc.y = fmaf(zv.y, wk[j].y, acc.y);
                acc.z = fmaf(zv.z, wk[j].z, acc.z);
                acc.w = fmaf(zv.w, wk[j].w, acc.w);
            }
        }
        float s = (acc.x + acc.y) + (acc.z + acc.w);
        s += __shfl_xor(s, 1, 64);
        s += __shfl_xor(s, 2, 64);    // all 4 quad lanes now hold the row dot
        s += bb;

        int bl = -1;
        unsigned long long key = 0ull;
        if (valid && ll == 0) {
            loc[row] = s;
            bl = bag[row];
            key = ((unsigned long long)fkey(s) << 32) | (unsigned)(N - 1 - (int)row);
        }
        // segmented suffix-max across the 16 row owners (lanes 0,4,...,60)
        #pragma unroll
        for (int off = 4; off <= 32; off <<= 1) {
            unsigned long long okey = __shfl_down(key, off, 64);
            int obag = __shfl_down(bl, off, 64);
            if (obag == bl && okey > key) key = okey;
        }
        int pbag = __shfl_up(bl, 4, 64);
        bool head = valid && (ll == 0) && (rowslot == 0 || pbag != bl);
        if (head) atomicMax(&packed[bl], key);
    }
}

// One block per bag: copy the argmax row of each array (zeros if bag empty).
__global__ __launch_bounds__(256) void gather_kernel(
    const float* __restrict__ z, const float* __restrict__ inst,
    const float* __restrict__ mu, const float* __restrict__ stdv,
    const unsigned long long* __restrict__ packed,
    float* __restrict__ oM, float* __restrict__ oInst, float* __restrict__ oZ,
    float* __restrict__ oMu, float* __restrict__ oStd, int N)
{
    int bagi = blockIdx.x;
    unsigned long long p = packed[bagi];
    bool empty = (p == 0ull);
    long long ac = empty ? 0 : (long long)(N - 1 - (int)(unsigned)(p & 0xFFFFFFFFull));
    const float4 zero4 = make_float4(0.f, 0.f, 0.f, 0.f);
    int t = threadIdx.x;
    if (t < 128) {
        float4 v = empty ? zero4 : ((const float4*)(inst + ac * FF))[t];
        ((float4*)(oInst + (long long)bagi * FF))[t] = v;
    } else if (t < 160) {
        int k = t - 128;
        float4 v = empty ? zero4 : ((const float4*)(z + ac * DD))[k];
        ((float4*)(oZ + (long long)bagi * DD))[k] = v;
    } else if (t < 192) {
        int k = t - 160;
        float4 v = empty ? zero4 : ((const float4*)(mu + ac * DD))[k];
        ((float4*)(oMu + (long long)bagi * DD))[k] = v;
    } else if (t < 224) {
        int k = t - 192;
        float4 v = empty ? zero4 : ((const float4*)(stdv + ac * DD))[k];
        ((float4*)(oStd + (long long)bagi * DD))[k] = v;
    } else if (t == 224) {
        oM[bagi] = empty ? 0.f : fkey_inv((unsigned)(p >> 32));
    }
}

extern "C" void kernel_launch(void* const* d_in, const int* in_sizes, int n_in,
                              void* d_out, int out_size, void* d_ws, size_t ws_size,
                              hipStream_t stream) {
    const float* z    = (const float*)d_in[0];
    const int*   bag  = (const int*)d_in[1];
    const float* inst = (const float*)d_in[2];
    const float* mu   = (const float*)d_in[3];
    const float* stdv = (const float*)d_in[4];
    const float* W    = (const float*)d_in[5];
    const float* b    = (const float*)d_in[6];
    int N = in_sizes[1];

    float* out = (float*)d_out;
    // Output layout (flat, return order): M | max_instances | max_z_ins | loc_ins | mu | std
    long long off_inst = BAGS;
    long long off_z    = off_inst + (long long)BAGS * FF;
    long long off_loc  = off_z    + (long long)BAGS * DD;
    long long off_mu   = off_loc  + N;
    long long off_std  = off_mu   + (long long)BAGS * DD;

    unsigned long long* packed = (unsigned long long*)d_ws;
    float* loc = out + off_loc;

    hipMemsetAsync(packed, 0, BAGS * sizeof(unsigned long long), stream);
    int blocks = (N + 255) / 256;
    loc_seg_kernel<<<blocks, 256, 0, stream>>>(z, bag, W, b, loc, packed, N);
    gather_kernel<<<BAGS, 256, 0, stream>>>(z, inst, mu, stdv, packed,
                                            out, out + off_inst, out + off_z,
                                            out + off_mu, out + off_std, N);
}